// Round 1
// baseline (974.667 us; speedup 1.0000x reference)
//
#include <hip/hip_runtime.h>
#include <math.h>

// LinearAttentionBlock fused fp32 baseline.
// B=16, N=8192, D=128, H=4, dh=32, FF=512.
//
// K1: per-block partial KV (H x 32 x 32) + Ksum over 256 tokens -> ws partials
// K2: reduce 32 partials per (b,h) -> KV, Ksum
// K3: per 64-token tile: Q=phi(x@Wq); attn=(Q@KV)/max(Q.Ksum,1e-6); @Wo;
//     +x; LN1; FF(relu(y@W1+b1)@W2+b2); +y; LN2 -> out. Fully fused in LDS.

#define D_MODEL 128
#define N_SEQ   8192
#define NB      16

__device__ __forceinline__ float phi_fn(float v) {
    // elu(v)+1 : v>0 -> v+1 ; v<=0 -> exp(v)
    return v > 0.f ? v + 1.f : __expf(v);
}

// ---------------- K1: K/V projection + partial KV accumulation ----------------
// grid 512 (32 per batch), 256 threads, 256 tokens per block (4 sub-tiles of 64)
__global__ __launch_bounds__(256, 2) void k1_kv(
    const float* __restrict__ x, const float* __restrict__ Wk,
    const float* __restrict__ Wv, float* __restrict__ partKV,
    float* __restrict__ partKs) {
    __shared__ float bufK[64][129];  // holds x tile, then K tile
    __shared__ float bufV[64][129];

    const int t = threadIdx.x;
    const int blk = blockIdx.x;
    const int b = blk >> 5;            // 32 blocks per batch
    const int tile0 = (blk & 31) * 4;  // first 64-token sub-tile index
    const int j2 = t & 63;             // dim pair base (j2, j2+64)
    const int tg = t >> 6;             // wave id: token parity group / head

    const int h = tg;          // phase D: head = wave
    const int dd = t & 31;     // phase D: d index
    const int mhalf = (t >> 5) & 1;

    float accKV[16];
#pragma unroll
    for (int i = 0; i < 16; i++) accKV[i] = 0.f;
    float accKs = 0.f;

    for (int sub = 0; sub < 4; ++sub) {
        const size_t tok0 = ((size_t)b << 13) + (size_t)(tile0 + sub) * 64;
        const float* xb = x + tok0 * D_MODEL;
        // load 64x128 x-tile (float4 global, scalar LDS due to pad)
        for (int i = t; i < 2048; i += 256) {
            float4 v = ((const float4*)xb)[i];
            int row = i >> 5, c4 = (i & 31) << 2;
            float* p = &bufK[row][c4];
            p[0] = v.x; p[1] = v.y; p[2] = v.z; p[3] = v.w;
        }
        __syncthreads();

        // K,V projections: 2 dims x 16 tokens per thread
        float aK[16][2], aV[16][2];
#pragma unroll
        for (int i = 0; i < 16; i++) { aK[i][0] = aK[i][1] = aV[i][0] = aV[i][1] = 0.f; }
        for (int k = 0; k < 128; k++) {
            float wk0 = Wk[k * 128 + j2], wk1 = Wk[k * 128 + j2 + 64];
            float wv0 = Wv[k * 128 + j2], wv1 = Wv[k * 128 + j2 + 64];
#pragma unroll
            for (int i = 0; i < 16; i++) {
                float xv = bufK[i * 4 + tg][k];
                aK[i][0] += xv * wk0; aK[i][1] += xv * wk1;
                aV[i][0] += xv * wv0; aV[i][1] += xv * wv1;
            }
        }
        __syncthreads();  // done reading x
        // stage phi(K) into bufK, V into bufV
#pragma unroll
        for (int i = 0; i < 16; i++) {
            int m = i * 4 + tg;
            bufK[m][j2]      = phi_fn(aK[i][0]);
            bufK[m][j2 + 64] = phi_fn(aK[i][1]);
            bufV[m][j2]      = aV[i][0];
            bufV[m][j2 + 64] = aV[i][1];
        }
        __syncthreads();
        // accumulate partial KV[h][dd][m], Ksum[h][dd]
        for (int tt = 0; tt < 64; ++tt) {
            float kv = bufK[tt][h * 32 + dd];
            accKs += kv;  // only mhalf==0 copy is written out
            const float* vr = &bufV[tt][h * 32 + mhalf * 16];
#pragma unroll
            for (int mm = 0; mm < 16; mm++) accKV[mm] += kv * vr[mm];
        }
        __syncthreads();  // before next sub-tile overwrites LDS
    }
    float* p = partKV + ((size_t)blk << 12) + (h << 10) + (dd << 5) + mhalf * 16;
#pragma unroll
    for (int mm = 0; mm < 16; mm++) p[mm] = accKV[mm];
    if (mhalf == 0) partKs[(blk << 7) + (h << 5) + dd] = accKs;
}

// ---------------- K2: reduce partials ----------------
__global__ void k2_reduce(const float* __restrict__ partKV,
                          const float* __restrict__ partKs,
                          float* __restrict__ KV, float* __restrict__ Ks) {
    const int bh = blockIdx.x;  // 64 = 16*4
    const int b = bh >> 2, h = bh & 3;
    for (int idx = threadIdx.x; idx < 1024; idx += 256) {
        float s = 0.f;
        for (int i = 0; i < 32; i++)
            s += partKV[(((size_t)(b * 32 + i)) << 12) + (h << 10) + idx];
        KV[((size_t)bh << 10) + idx] = s;
    }
    if (threadIdx.x < 32) {
        float s = 0.f;
        for (int i = 0; i < 32; i++)
            s += partKs[((b * 32 + i) << 7) + (h << 5) + threadIdx.x];
        Ks[(bh << 5) + threadIdx.x] = s;
    }
}

// ---------------- LN helper (stats into stats[][2]) ----------------
__device__ __forceinline__ void ln_stats(float (*bufX)[129], float (*red1)[4],
                                         float (*red2)[4], float (*stats)[2], int t) {
    int m = t & 63, q = t >> 6;
    float s1 = 0.f, s2 = 0.f;
    const float* row = bufX[m] + q * 32;
#pragma unroll
    for (int jj = 0; jj < 32; jj++) { float v = row[jj]; s1 += v; s2 += v * v; }
    red1[m][q] = s1; red2[m][q] = s2;
    __syncthreads();
    if (t < 64) {
        float a = red1[t][0] + red1[t][1] + red1[t][2] + red1[t][3];
        float c = red2[t][0] + red2[t][1] + red2[t][2] + red2[t][3];
        float mu = a * (1.f / 128.f);
        float var = c * (1.f / 128.f) - mu * mu;
        stats[t][0] = mu;
        stats[t][1] = rsqrtf(var + 1e-5f);
    }
    __syncthreads();
}

// ---------------- K3: Q + attn + Wo + LN1 + FF + LN2 ----------------
// grid 2048 (128 per batch), 256 threads, 64 tokens per block
__global__ __launch_bounds__(256, 2) void k3_main(
    const float* __restrict__ x, const float* __restrict__ Wq,
    const float* __restrict__ Wo, const float* __restrict__ KV,
    const float* __restrict__ Ks, const float* __restrict__ ln1g,
    const float* __restrict__ ln1b, const float* __restrict__ W1,
    const float* __restrict__ b1, const float* __restrict__ W2,
    const float* __restrict__ b2, const float* __restrict__ ln2g,
    const float* __restrict__ ln2b, float* __restrict__ out) {
    __shared__ float bufX[64][129];  // x -> residual -> y -> r2
    __shared__ float bufQ[64][129];  // Q -> attn -> relu hidden chunks
    __shared__ float den[64][4];
    __shared__ float red1[64][4];
    __shared__ float red2[64][4];
    __shared__ float stats[64][2];

    const int t = threadIdx.x;
    const int blk = blockIdx.x;
    const int b = blk >> 7;
    const int n0 = (blk & 127) << 6;
    const size_t tokbase = ((size_t)b << 13) + n0;
    const float* xb = x + tokbase * D_MODEL;

    for (int i = t; i < 2048; i += 256) {
        float4 v = ((const float4*)xb)[i];
        int row = i >> 5, c4 = (i & 31) << 2;
        float* p = &bufX[row][c4];
        p[0] = v.x; p[1] = v.y; p[2] = v.z; p[3] = v.w;
    }
    __syncthreads();

    const int jq = t & 31;    // 4-dim blocking: jq, +32, +64, +96
    const int tg8 = t >> 5;   // token mod 8
    const int j128 = t & 127; // 1-dim layout for attn
    const int tg2 = t >> 7;   // token parity

    // ---- Q = phi(x @ Wq) ----
    {
        float acc[8][4];
#pragma unroll
        for (int i = 0; i < 8; i++) { acc[i][0] = acc[i][1] = acc[i][2] = acc[i][3] = 0.f; }
        for (int k = 0; k < 128; k++) {
            const float* wr = Wq + k * 128;
            float w0 = wr[jq], w1 = wr[jq + 32], w2 = wr[jq + 64], w3 = wr[jq + 96];
#pragma unroll
            for (int i = 0; i < 8; i++) {
                float xv = bufX[i * 8 + tg8][k];
                acc[i][0] += xv * w0; acc[i][1] += xv * w1;
                acc[i][2] += xv * w2; acc[i][3] += xv * w3;
            }
        }
#pragma unroll
        for (int i = 0; i < 8; i++) {
            int m = i * 8 + tg8;
            bufQ[m][jq]      = phi_fn(acc[i][0]);
            bufQ[m][jq + 32] = phi_fn(acc[i][1]);
            bufQ[m][jq + 64] = phi_fn(acc[i][2]);
            bufQ[m][jq + 96] = phi_fn(acc[i][3]);
        }
    }
    __syncthreads();

    // ---- denom = max(Q . Ksum, 1e-6) ----
    {
        int m = t & 63, hh = t >> 6;
        const float* ks = Ks + ((b << 2) + hh) * 32;
        float s = 0.f;
#pragma unroll
        for (int d = 0; d < 32; d++) s += bufQ[m][hh * 32 + d] * ks[d];
        den[m][hh] = fmaxf(s, 1e-6f);
    }
    __syncthreads();

    // ---- attn = (Q @ KV) / den ----
    float attnv[32];
    {
        int hh = j128 >> 5;
        int mc = j128 & 31;
        const float* kvp = KV + (((size_t)(b * 4 + hh)) << 10) + mc;
        float kvcol[32];
#pragma unroll
        for (int d = 0; d < 32; d++) kvcol[d] = kvp[d << 5];
#pragma unroll 4
        for (int i = 0; i < 32; i++) {
            int m = i * 2 + tg2;
            const float* qrow = &bufQ[m][hh << 5];
            float s = 0.f;
#pragma unroll
            for (int d = 0; d < 32; d++) s += qrow[d] * kvcol[d];
            attnv[i] = s / den[m][hh];
        }
    }
    __syncthreads();
#pragma unroll
    for (int i = 0; i < 32; i++) bufQ[i * 2 + tg2][j128] = attnv[i];
    __syncthreads();

    // ---- o = attn @ Wo ; residual r = x + o ----
    {
        float acc[8][4];
#pragma unroll
        for (int i = 0; i < 8; i++) { acc[i][0] = acc[i][1] = acc[i][2] = acc[i][3] = 0.f; }
        for (int k = 0; k < 128; k++) {
            const float* wr = Wo + k * 128;
            float w0 = wr[jq], w1 = wr[jq + 32], w2 = wr[jq + 64], w3 = wr[jq + 96];
#pragma unroll
            for (int i = 0; i < 8; i++) {
                float xv = bufQ[i * 8 + tg8][k];
                acc[i][0] += xv * w0; acc[i][1] += xv * w1;
                acc[i][2] += xv * w2; acc[i][3] += xv * w3;
            }
        }
#pragma unroll
        for (int i = 0; i < 8; i++) {
            int m = i * 8 + tg8;
            bufX[m][jq]      += acc[i][0];
            bufX[m][jq + 32] += acc[i][1];
            bufX[m][jq + 64] += acc[i][2];
            bufX[m][jq + 96] += acc[i][3];
        }
    }
    __syncthreads();

    // ---- LN1 in place ----
    ln_stats(bufX, red1, red2, stats, t);
    {
        float g0 = ln1g[jq], g1 = ln1g[jq + 32], g2 = ln1g[jq + 64], g3 = ln1g[jq + 96];
        float c0 = ln1b[jq], c1 = ln1b[jq + 32], c2 = ln1b[jq + 64], c3 = ln1b[jq + 96];
#pragma unroll
        for (int i = 0; i < 8; i++) {
            int m = i * 8 + tg8;
            float mu = stats[m][0], rs = stats[m][1];
            bufX[m][jq]      = (bufX[m][jq] - mu) * rs * g0 + c0;
            bufX[m][jq + 32] = (bufX[m][jq + 32] - mu) * rs * g1 + c1;
            bufX[m][jq + 64] = (bufX[m][jq + 64] - mu) * rs * g2 + c2;
            bufX[m][jq + 96] = (bufX[m][jq + 96] - mu) * rs * g3 + c3;
        }
    }
    __syncthreads();

    // ---- FF: f = relu(y@W1+b1)@W2 (accumulated over 4 hidden chunks) ----
    float facc[8][4];
#pragma unroll
    for (int i = 0; i < 8; i++) { facc[i][0] = facc[i][1] = facc[i][2] = facc[i][3] = 0.f; }
    for (int ch = 0; ch < 4; ++ch) {
        float hacc[8][4];
#pragma unroll
        for (int i = 0; i < 8; i++) { hacc[i][0] = hacc[i][1] = hacc[i][2] = hacc[i][3] = 0.f; }
        for (int k = 0; k < 128; k++) {
            const float* wr = W1 + k * 512 + ch * 128;
            float w0 = wr[jq], w1 = wr[jq + 32], w2 = wr[jq + 64], w3 = wr[jq + 96];
#pragma unroll
            for (int i = 0; i < 8; i++) {
                float xv = bufX[i * 8 + tg8][k];
                hacc[i][0] += xv * w0; hacc[i][1] += xv * w1;
                hacc[i][2] += xv * w2; hacc[i][3] += xv * w3;
            }
        }
        __syncthreads();  // prior chunk's bufQ reads complete
        {
            const float* bc = b1 + ch * 128;
            float c0 = bc[jq], c1 = bc[jq + 32], c2 = bc[jq + 64], c3 = bc[jq + 96];
#pragma unroll
            for (int i = 0; i < 8; i++) {
                int m = i * 8 + tg8;
                bufQ[m][jq]      = fmaxf(hacc[i][0] + c0, 0.f);
                bufQ[m][jq + 32] = fmaxf(hacc[i][1] + c1, 0.f);
                bufQ[m][jq + 64] = fmaxf(hacc[i][2] + c2, 0.f);
                bufQ[m][jq + 96] = fmaxf(hacc[i][3] + c3, 0.f);
            }
        }
        __syncthreads();
        for (int u = 0; u < 128; u++) {
            const float* wr = W2 + (ch * 128 + u) * 128;
            float w0 = wr[jq], w1 = wr[jq + 32], w2 = wr[jq + 64], w3 = wr[jq + 96];
#pragma unroll
            for (int i = 0; i < 8; i++) {
                float hv = bufQ[i * 8 + tg8][u];
                facc[i][0] += hv * w0; facc[i][1] += hv * w1;
                facc[i][2] += hv * w2; facc[i][3] += hv * w3;
            }
        }
    }
    // r2 = y + f + b2 -> bufX
    {
        float c0 = b2[jq], c1 = b2[jq + 32], c2 = b2[jq + 64], c3 = b2[jq + 96];
#pragma unroll
        for (int i = 0; i < 8; i++) {
            int m = i * 8 + tg8;
            bufX[m][jq]      += facc[i][0] + c0;
            bufX[m][jq + 32] += facc[i][1] + c1;
            bufX[m][jq + 64] += facc[i][2] + c2;
            bufX[m][jq + 96] += facc[i][3] + c3;
        }
    }
    __syncthreads();

    // ---- LN2 + store ----
    ln_stats(bufX, red1, red2, stats, t);
    {
        float g0 = ln2g[jq], g1 = ln2g[jq + 32], g2 = ln2g[jq + 64], g3 = ln2g[jq + 96];
        float c0 = ln2b[jq], c1 = ln2b[jq + 32], c2 = ln2b[jq + 64], c3 = ln2b[jq + 96];
        float* ob = out + tokbase * D_MODEL;
#pragma unroll
        for (int i = 0; i < 8; i++) {
            int m = i * 8 + tg8;
            float mu = stats[m][0], rs = stats[m][1];
            ob[m * 128 + jq]      = (bufX[m][jq] - mu) * rs * g0 + c0;
            ob[m * 128 + jq + 32] = (bufX[m][jq + 32] - mu) * rs * g1 + c1;
            ob[m * 128 + jq + 64] = (bufX[m][jq + 64] - mu) * rs * g2 + c2;
            ob[m * 128 + jq + 96] = (bufX[m][jq + 96] - mu) * rs * g3 + c3;
        }
    }
}

extern "C" void kernel_launch(void* const* d_in, const int* in_sizes, int n_in,
                              void* d_out, int out_size, void* d_ws, size_t ws_size,
                              hipStream_t stream) {
    const float* x    = (const float*)d_in[0];
    const float* Wq   = (const float*)d_in[1];
    const float* Wk   = (const float*)d_in[2];
    const float* Wv   = (const float*)d_in[3];
    const float* Wo   = (const float*)d_in[4];
    const float* ln1g = (const float*)d_in[5];
    const float* ln1b = (const float*)d_in[6];
    const float* W1   = (const float*)d_in[7];
    const float* b1   = (const float*)d_in[8];
    const float* W2   = (const float*)d_in[9];
    const float* b2   = (const float*)d_in[10];
    const float* ln2g = (const float*)d_in[11];
    const float* ln2b = (const float*)d_in[12];
    float* out = (float*)d_out;

    float* partKV = (float*)d_ws;                       // 512*4096
    float* partKs = partKV + (size_t)512 * 4096;        // 512*128
    float* KVf    = partKs + (size_t)512 * 128;         // 64*1024
    float* Ksf    = KVf + (size_t)64 * 1024;            // 64*32

    k1_kv<<<512, 256, 0, stream>>>(x, Wk, Wv, partKV, partKs);
    k2_reduce<<<64, 256, 0, stream>>>(partKV, partKs, KVf, Ksf);
    k3_main<<<2048, 256, 0, stream>>>(x, Wq, Wo, KVf, Ksf, ln1g, ln1b, W1, b1,
                                      W2, b2, ln2g, ln2b, out);
}

// Round 2
// 239.232 us; speedup vs baseline: 4.0742x; 4.0742x over previous
//
#include <hip/hip_runtime.h>
#include <math.h>

// LinearAttentionBlock — bf16 MFMA version.
// B=16, N=8192, D=128, H=4, dh=32, FF=512. mfma_f32_16x16x32_bf16 throughout.
// kw: convert+transpose weights to bf16 [n][k] layout.
// k1: K=phi(x@Wk), V=x@Wv via MFMA -> K^T/V^T LDS -> partial KV (MFMA over token dim) + Ksum.
// k2: reduce partials -> KVt bf16 [m][d], Ksum f32.
// k3: wave-private fused: Q -> denom(shfl) -> attn -> Wo+res -> LN1(shfl) -> FF -> res -> LN2 -> out.

using bfrag = __attribute__((ext_vector_type(8))) short;   // 8 bf16 (MFMA A/B)
using sh4   = __attribute__((ext_vector_type(4))) short;   // 4 bf16 (8B LDS write)
using ffrag = __attribute__((ext_vector_type(4))) float;   // MFMA C/D

#define MFMA(a, b, c) __builtin_amdgcn_mfma_f32_16x16x32_bf16((a), (b), (c), 0, 0, 0)

__device__ __forceinline__ float phi_fn(float v) { return v > 0.f ? v + 1.f : __expf(v); }

__device__ __forceinline__ short f2bf(float f) {
    union { float f; unsigned u; } v; v.f = f;
    unsigned r = v.u + 0x7fffu + ((v.u >> 16) & 1u);  // RNE
    return (short)(r >> 16);
}
__device__ __forceinline__ float bf2f(short s) {
    union { unsigned u; float f; } v; v.u = ((unsigned)(unsigned short)s) << 16;
    return v.f;
}

// ---------------- kw: weight convert + transpose ----------------
__global__ void kw_conv(const float* __restrict__ Wq, const float* __restrict__ Wk,
                        const float* __restrict__ Wv, const float* __restrict__ Wo,
                        const float* __restrict__ W1, const float* __restrict__ W2,
                        short* __restrict__ Wqt, short* __restrict__ Wkt,
                        short* __restrict__ Wvt, short* __restrict__ Wot,
                        short* __restrict__ W1t, short* __restrict__ W2t) {
    int i = blockIdx.x * 256 + threadIdx.x;
    if (i < 65536) {
        int mat = i >> 14, q = i & 16383, n = q >> 7, k = q & 127;
        const float* S = mat == 0 ? Wq : mat == 1 ? Wk : mat == 2 ? Wv : Wo;
        short* D = mat == 0 ? Wqt : mat == 1 ? Wkt : mat == 2 ? Wvt : Wot;
        D[n * 128 + k] = f2bf(S[k * 128 + n]);
    } else if (i < 131072) {
        int q = i - 65536, n = q >> 7, k = q & 127;
        W1t[n * 128 + k] = f2bf(W1[k * 512 + n]);
    } else {
        int q = i - 131072, n = q >> 9, k = q & 511;
        W2t[n * 512 + k] = f2bf(W2[k * 128 + n]);
    }
}

// ---------------- k1: K/V proj + partial KV ----------------
// 512 blocks x 256 thr; 256 tokens/block (4 subtiles of 64); wave w = rows 16w..16w+15; head = w.
__global__ __launch_bounds__(256, 2) void k1_kv(
    const float* __restrict__ x, const short* __restrict__ Wkt,
    const short* __restrict__ Wvt, short* __restrict__ partKV,
    float* __restrict__ partKs) {
    __shared__ short sx[64][136];
    __shared__ short Kt[128][72];  // [dim][token]  (144B rows: 16B aligned, 9-slot rotation)
    __shared__ short Vt[128][72];

    const int t = threadIdx.x, w = t >> 6, l = t & 63, lr = l & 15, lg = l >> 4;
    const int blk = blockIdx.x, b = blk >> 5;
    const size_t tok0 = ((size_t)b << 13) + (size_t)(blk & 31) * 256;

    ffrag kvacc[2][2];
#pragma unroll
    for (int dt = 0; dt < 2; dt++)
#pragma unroll
        for (int mt = 0; mt < 2; mt++) kvacc[dt][mt] = ffrag{0.f, 0.f, 0.f, 0.f};
    float accKs[8];
#pragma unroll
    for (int i = 0; i < 8; i++) accKs[i] = 0.f;

    for (int s = 0; s < 4; ++s) {
        // stage own rows (wave-private)
        const float* xb = x + (tok0 + (size_t)s * 64 + w * 16) * 128;
#pragma unroll
        for (int it = 0; it < 4; ++it) {
            int idx = it * 64 + l;  // 0..255
            int row = idx >> 4, c8 = (idx & 15) * 8;
            const float4* p = (const float4*)(xb + row * 128 + c8);
            float4 v0 = p[0], v1 = p[1];
            bfrag sv;
            sv[0] = f2bf(v0.x); sv[1] = f2bf(v0.y); sv[2] = f2bf(v0.z); sv[3] = f2bf(v0.w);
            sv[4] = f2bf(v1.x); sv[5] = f2bf(v1.y); sv[6] = f2bf(v1.z); sv[7] = f2bf(v1.w);
            *(bfrag*)&sx[w * 16 + row][c8] = sv;
        }
        bfrag xf[4];
#pragma unroll
        for (int kk = 0; kk < 4; kk++)
            xf[kk] = *(const bfrag*)&sx[w * 16 + lr][kk * 32 + lg * 8];
        const int toff = w * 16 + lg * 4;
#pragma unroll
        for (int n0 = 0; n0 < 8; n0++) {
            ffrag ck = {0.f, 0.f, 0.f, 0.f}, cv = {0.f, 0.f, 0.f, 0.f};
#pragma unroll
            for (int kk = 0; kk < 4; kk++) {
                bfrag bk = *(const bfrag*)(Wkt + (n0 * 16 + lr) * 128 + kk * 32 + lg * 8);
                bfrag bv = *(const bfrag*)(Wvt + (n0 * 16 + lr) * 128 + kk * 32 + lg * 8);
                ck = MFMA(xf[kk], bk, ck);
                cv = MFMA(xf[kk], bv, cv);
            }
            sh4 ks, vs;
#pragma unroll
            for (int j = 0; j < 4; j++) {
                float pv = phi_fn(ck[j]);
                accKs[n0] += pv;
                ks[j] = f2bf(pv);
                vs[j] = f2bf(cv[j]);
            }
            *(sh4*)&Kt[n0 * 16 + lr][toff] = ks;
            *(sh4*)&Vt[n0 * 16 + lr][toff] = vs;
        }
        __syncthreads();
        // KV accumulate: A=Kt rows (head dims), B=Vt rows, K-dim = 64 tokens
#pragma unroll
        for (int kk = 0; kk < 2; kk++) {
            bfrag ka0 = *(const bfrag*)&Kt[w * 32 + lr][kk * 32 + lg * 8];
            bfrag ka1 = *(const bfrag*)&Kt[w * 32 + 16 + lr][kk * 32 + lg * 8];
            bfrag vb0 = *(const bfrag*)&Vt[w * 32 + lr][kk * 32 + lg * 8];
            bfrag vb1 = *(const bfrag*)&Vt[w * 32 + 16 + lr][kk * 32 + lg * 8];
            kvacc[0][0] = MFMA(ka0, vb0, kvacc[0][0]);
            kvacc[0][1] = MFMA(ka0, vb1, kvacc[0][1]);
            kvacc[1][0] = MFMA(ka1, vb0, kvacc[1][0]);
            kvacc[1][1] = MFMA(ka1, vb1, kvacc[1][1]);
        }
        __syncthreads();
    }
    short* pk = partKV + ((size_t)(blk * 4 + w) << 10);
#pragma unroll
    for (int dt = 0; dt < 2; dt++)
#pragma unroll
        for (int mt = 0; mt < 2; mt++)
#pragma unroll
            for (int j = 0; j < 4; j++)
                pk[(dt * 16 + lg * 4 + j) * 32 + mt * 16 + lr] = f2bf(kvacc[dt][mt][j]);
#pragma unroll
    for (int n0 = 0; n0 < 8; n0++) {
        float v = accKs[n0];
        v += __shfl_xor(v, 16);
        v += __shfl_xor(v, 32);
        if (l < 16) partKs[(blk * 4 + w) * 128 + n0 * 16 + l] = v;
    }
}

// ---------------- k2: reduce partials ----------------
__global__ void k2_red(const short* __restrict__ partKV, const float* __restrict__ partKs,
                       short* __restrict__ KVt, float* __restrict__ Ksf) {
    int bh = blockIdx.x, b = bh >> 2, h = bh & 3, t = threadIdx.x;
    for (int idx = t; idx < 1024; idx += 256) {
        int d = idx >> 5, m = idx & 31;
        float s = 0.f;
        for (int i = 0; i < 32; i++)
            s += bf2f(partKV[((size_t)((b * 32 + i) * 4 + h) << 10) + idx]);
        KVt[((size_t)bh << 10) + m * 32 + d] = f2bf(s);  // transposed [m][d]
    }
    if (t < 32) {
        float s = 0.f;
        for (int i = 0; i < 32; i++)
            for (int w = 0; w < 4; w++)
                s += partKs[((b * 32 + i) * 4 + w) * 128 + h * 32 + t];
        Ksf[bh * 32 + t] = s;
    }
}

// ---------------- k3: fused main (zero barriers; wave-private) ----------------
// 1024 blocks x 256 thr; 128 tokens/block; wave w owns rows 32w..32w+31.
__global__ __launch_bounds__(256, 2) void k3_main(
    const float* __restrict__ x, const short* __restrict__ Wqt,
    const short* __restrict__ Wot, const short* __restrict__ KVt,
    const float* __restrict__ Ksf, const float* __restrict__ ln1g,
    const float* __restrict__ ln1b, const short* __restrict__ W1t,
    const float* __restrict__ b1, const short* __restrict__ W2t,
    const float* __restrict__ b2, const float* __restrict__ ln2g,
    const float* __restrict__ ln2b, float* __restrict__ out) {
    __shared__ short sbuf[128][136];  // x -> Q -> attn -> h chunks
    __shared__ short ybuf[128][136];  // y (LN1 out)
    __shared__ float den[128][5];

    const int t = threadIdx.x, w = t >> 6, l = t & 63, lr = l & 15, lg = l >> 4;
    const int blk = blockIdx.x, b = blk >> 6;
    const size_t tok0 = ((size_t)b << 13) + (size_t)(blk & 63) * 128;
    const int R0 = w * 32;
    const float* xw = x + (tok0 + R0) * 128;

    // stage own 32 rows as bf16
#pragma unroll
    for (int it = 0; it < 8; ++it) {
        int idx = it * 64 + l;  // 0..511
        int row = idx >> 4, c8 = (idx & 15) * 8;
        const float4* p = (const float4*)(xw + row * 128 + c8);
        float4 v0 = p[0], v1 = p[1];
        bfrag sv;
        sv[0] = f2bf(v0.x); sv[1] = f2bf(v0.y); sv[2] = f2bf(v0.z); sv[3] = f2bf(v0.w);
        sv[4] = f2bf(v1.x); sv[5] = f2bf(v1.y); sv[6] = f2bf(v1.z); sv[7] = f2bf(v1.w);
        *(bfrag*)&sbuf[R0 + row][c8] = sv;
    }

    // ---- Q = phi(x@Wq), in place over x ----
    bfrag xf[2][4];
#pragma unroll
    for (int rt = 0; rt < 2; rt++)
#pragma unroll
        for (int kk = 0; kk < 4; kk++)
            xf[rt][kk] = *(const bfrag*)&sbuf[R0 + rt * 16 + lr][kk * 32 + lg * 8];
#pragma unroll
    for (int n0 = 0; n0 < 8; n0++) {
        ffrag c0 = {0.f, 0.f, 0.f, 0.f}, c1 = {0.f, 0.f, 0.f, 0.f};
#pragma unroll
        for (int kk = 0; kk < 4; kk++) {
            bfrag bw = *(const bfrag*)(Wqt + (n0 * 16 + lr) * 128 + kk * 32 + lg * 8);
            c0 = MFMA(xf[0][kk], bw, c0);
            c1 = MFMA(xf[1][kk], bw, c1);
        }
#pragma unroll
        for (int j = 0; j < 4; j++) {
            sbuf[R0 + lg * 4 + j][n0 * 16 + lr] = f2bf(phi_fn(c0[j]));
            sbuf[R0 + 16 + lg * 4 + j][n0 * 16 + lr] = f2bf(phi_fn(c1[j]));
        }
    }

    // ---- attn per head: denom (shfl) + Q@KV, in place over Q ----
#pragma unroll
    for (int h = 0; h < 4; h++) {
        bfrag qf0 = *(const bfrag*)&sbuf[R0 + lr][h * 32 + lg * 8];
        bfrag qf1 = *(const bfrag*)&sbuf[R0 + 16 + lr][h * 32 + lg * 8];
        const float4* kp = (const float4*)(Ksf + (b * 4 + h) * 32 + lg * 8);
        float4 ka = kp[0], kb = kp[1];
        float ksv[8] = {ka.x, ka.y, ka.z, ka.w, kb.x, kb.y, kb.z, kb.w};
        float p0 = 0.f, p1 = 0.f;
#pragma unroll
        for (int j = 0; j < 8; j++) {
            p0 += bf2f(qf0[j]) * ksv[j];
            p1 += bf2f(qf1[j]) * ksv[j];
        }
        p0 += __shfl_xor(p0, 16); p0 += __shfl_xor(p0, 32);
        p1 += __shfl_xor(p1, 16); p1 += __shfl_xor(p1, 32);
        if (l < 16) {
            den[R0 + l][h] = fmaxf(p0, 1e-6f);
            den[R0 + 16 + l][h] = fmaxf(p1, 1e-6f);
        }
        const ffrag fz = {0.f, 0.f, 0.f, 0.f};
#pragma unroll
        for (int mt = 0; mt < 2; mt++) {
            bfrag bkv = *(const bfrag*)(KVt + ((size_t)(b * 4 + h) << 10) + (mt * 16 + lr) * 32 + lg * 8);
            ffrag c0 = MFMA(qf0, bkv, fz);
            ffrag c1 = MFMA(qf1, bkv, fz);
#pragma unroll
            for (int j = 0; j < 4; j++) {
                int row0 = R0 + lg * 4 + j;
                int row1 = R0 + 16 + lg * 4 + j;
                sbuf[row0][h * 32 + mt * 16 + lr] = f2bf(c0[j] / den[row0][h]);
                sbuf[row1][h * 32 + mt * 16 + lr] = f2bf(c1[j] / den[row1][h]);
            }
        }
    }

    // ---- Wo + residual + LN1 ----
    bfrag af[2][4];
#pragma unroll
    for (int rt = 0; rt < 2; rt++)
#pragma unroll
        for (int kk = 0; kk < 4; kk++)
            af[rt][kk] = *(const bfrag*)&sbuf[R0 + rt * 16 + lr][kk * 32 + lg * 8];
    float r[2][8][4];
#pragma unroll
    for (int n0 = 0; n0 < 8; n0++) {
        ffrag c0 = {0.f, 0.f, 0.f, 0.f}, c1 = {0.f, 0.f, 0.f, 0.f};
#pragma unroll
        for (int kk = 0; kk < 4; kk++) {
            bfrag bw = *(const bfrag*)(Wot + (n0 * 16 + lr) * 128 + kk * 32 + lg * 8);
            c0 = MFMA(af[0][kk], bw, c0);
            c1 = MFMA(af[1][kk], bw, c1);
        }
#pragma unroll
        for (int j = 0; j < 4; j++) {
            r[0][n0][j] = c0[j] + x[(tok0 + R0 + lg * 4 + j) * 128 + n0 * 16 + lr];
            r[1][n0][j] = c1[j] + x[(tok0 + R0 + 16 + lg * 4 + j) * 128 + n0 * 16 + lr];
        }
    }
    float mu[2][4], rs[2][4];
#pragma unroll
    for (int rt = 0; rt < 2; rt++)
#pragma unroll
        for (int j = 0; j < 4; j++) {
            float s1 = 0.f, s2 = 0.f;
#pragma unroll
            for (int n0 = 0; n0 < 8; n0++) { float v = r[rt][n0][j]; s1 += v; s2 += v * v; }
#pragma unroll
            for (int d = 1; d < 16; d <<= 1) { s1 += __shfl_xor(s1, d); s2 += __shfl_xor(s2, d); }
            float m_ = s1 * (1.f / 128.f);
            mu[rt][j] = m_;
            rs[rt][j] = rsqrtf(s2 * (1.f / 128.f) - m_ * m_ + 1e-5f);
        }
#pragma unroll
    for (int n0 = 0; n0 < 8; n0++) {
        int c = n0 * 16 + lr;
        float g = ln1g[c], bb = ln1b[c];
#pragma unroll
        for (int rt = 0; rt < 2; rt++)
#pragma unroll
            for (int j = 0; j < 4; j++) {
                int row = R0 + rt * 16 + lg * 4 + j;
                ybuf[row][c] = f2bf((r[rt][n0][j] - mu[rt][j]) * rs[rt][j] * g + bb);
            }
    }

    // ---- FF: h = relu(y@W1+b1) (4 chunks of 128), f = h@W2 accumulated ----
    bfrag yf[2][4];
#pragma unroll
    for (int rt = 0; rt < 2; rt++)
#pragma unroll
        for (int kk = 0; kk < 4; kk++)
            yf[rt][kk] = *(const bfrag*)&ybuf[R0 + rt * 16 + lr][kk * 32 + lg * 8];
    ffrag facc[2][8];
#pragma unroll
    for (int rt = 0; rt < 2; rt++)
#pragma unroll
        for (int n0 = 0; n0 < 8; n0++) facc[rt][n0] = ffrag{0.f, 0.f, 0.f, 0.f};
    for (int ch = 0; ch < 4; ++ch) {
#pragma unroll
        for (int n0 = 0; n0 < 8; n0++) {
            ffrag c0 = {0.f, 0.f, 0.f, 0.f}, c1 = {0.f, 0.f, 0.f, 0.f};
#pragma unroll
            for (int kk = 0; kk < 4; kk++) {
                bfrag bw = *(const bfrag*)(W1t + (ch * 128 + n0 * 16 + lr) * 128 + kk * 32 + lg * 8);
                c0 = MFMA(yf[0][kk], bw, c0);
                c1 = MFMA(yf[1][kk], bw, c1);
            }
            float bb = b1[ch * 128 + n0 * 16 + lr];
#pragma unroll
            for (int j = 0; j < 4; j++) {
                sbuf[R0 + lg * 4 + j][n0 * 16 + lr] = f2bf(fmaxf(c0[j] + bb, 0.f));
                sbuf[R0 + 16 + lg * 4 + j][n0 * 16 + lr] = f2bf(fmaxf(c1[j] + bb, 0.f));
            }
        }
        bfrag hf[2][4];
#pragma unroll
        for (int rt = 0; rt < 2; rt++)
#pragma unroll
            for (int kk = 0; kk < 4; kk++)
                hf[rt][kk] = *(const bfrag*)&sbuf[R0 + rt * 16 + lr][kk * 32 + lg * 8];
#pragma unroll
        for (int n0 = 0; n0 < 8; n0++) {
#pragma unroll
            for (int kk = 0; kk < 4; kk++) {
                bfrag bw = *(const bfrag*)(W2t + (n0 * 16 + lr) * 512 + ch * 128 + kk * 32 + lg * 8);
                facc[0][n0] = MFMA(hf[0][kk], bw, facc[0][n0]);
                facc[1][n0] = MFMA(hf[1][kk], bw, facc[1][n0]);
            }
        }
    }

    // ---- residual2 (in place into facc) + LN2 + store ----
#pragma unroll
    for (int n0 = 0; n0 < 8; n0++) {
        int c = n0 * 16 + lr;
        float bb = b2[c];
#pragma unroll
        for (int rt = 0; rt < 2; rt++)
#pragma unroll
            for (int j = 0; j < 4; j++) {
                int row = R0 + rt * 16 + lg * 4 + j;
                facc[rt][n0][j] = facc[rt][n0][j] + bf2f(ybuf[row][c]) + bb;
            }
    }
#pragma unroll
    for (int rt = 0; rt < 2; rt++)
#pragma unroll
        for (int j = 0; j < 4; j++) {
            float s1 = 0.f, s2 = 0.f;
#pragma unroll
            for (int n0 = 0; n0 < 8; n0++) { float v = facc[rt][n0][j]; s1 += v; s2 += v * v; }
#pragma unroll
            for (int d = 1; d < 16; d <<= 1) { s1 += __shfl_xor(s1, d); s2 += __shfl_xor(s2, d); }
            float m_ = s1 * (1.f / 128.f);
            mu[rt][j] = m_;
            rs[rt][j] = rsqrtf(s2 * (1.f / 128.f) - m_ * m_ + 1e-5f);
        }
#pragma unroll
    for (int n0 = 0; n0 < 8; n0++) {
        int c = n0 * 16 + lr;
        float g = ln2g[c], bb = ln2b[c];
#pragma unroll
        for (int rt = 0; rt < 2; rt++)
#pragma unroll
            for (int j = 0; j < 4; j++) {
                int row = R0 + rt * 16 + lg * 4 + j;
                out[(tok0 + row) * 128 + c] = (facc[rt][n0][j] - mu[rt][j]) * rs[rt][j] * g + bb;
            }
    }
}

extern "C" void kernel_launch(void* const* d_in, const int* in_sizes, int n_in,
                              void* d_out, int out_size, void* d_ws, size_t ws_size,
                              hipStream_t stream) {
    const float* x    = (const float*)d_in[0];
    const float* Wq   = (const float*)d_in[1];
    const float* Wk   = (const float*)d_in[2];
    const float* Wv   = (const float*)d_in[3];
    const float* Wo   = (const float*)d_in[4];
    const float* ln1g = (const float*)d_in[5];
    const float* ln1b = (const float*)d_in[6];
    const float* W1   = (const float*)d_in[7];
    const float* b1   = (const float*)d_in[8];
    const float* W2   = (const float*)d_in[9];
    const float* b2   = (const float*)d_in[10];
    const float* ln2g = (const float*)d_in[11];
    const float* ln2b = (const float*)d_in[12];
    float* out = (float*)d_out;

    // ws layout (~5.5 MB)
    short* partKV = (short*)d_ws;                       // 512*4*1024 bf16
    float* partKs = (float*)(partKV + 2097152);         // 512*4*128  f32
    short* KVt    = (short*)(partKs + 262144);          // 64*1024    bf16 (transposed [m][d])
    float* Ksf    = (float*)(KVt + 65536);              // 64*32      f32
    short* Wqt    = (short*)(Ksf + 2048);
    short* Wkt    = Wqt + 16384;
    short* Wvt    = Wkt + 16384;
    short* Wot    = Wvt + 16384;
    short* W1t    = Wot + 16384;                        // [512][128]
    short* W2t    = W1t + 65536;                        // [128][512]

    kw_conv<<<768, 256, 0, stream>>>(Wq, Wk, Wv, Wo, W1, W2, Wqt, Wkt, Wvt, Wot, W1t, W2t);
    k1_kv<<<512, 256, 0, stream>>>(x, Wkt, Wvt, partKV, partKs);
    k2_red<<<64, 256, 0, stream>>>(partKV, partKs, KVt, Ksf);
    k3_main<<<1024, 256, 0, stream>>>(x, Wqt, Wot, KVt, Ksf, ln1g, ln1b, W1t, b1,
                                      W2t, b2, ln2g, ln2b, out);
}